// Round 1
// baseline (5143.301 us; speedup 1.0000x reference)
//
#include <hip/hip_runtime.h>
#include <math.h>

#define BB 8
#define NT 1025
#define CD 512
#define NH 8
#define DHD 64
#define HW 1024
#define GS 32
#define FWD 17

__device__ __forceinline__ float gelu_exact(float x){
  return 0.5f * x * (1.0f + erff(x * 0.70710678118654752f));
}

// ---------------- GEMM: C[M,N] = A[M,K] @ B[K,N] (+bias, +gelu) ----------------
// N, K must be multiples of 64/16 (true here: N in {384,512}, K in {512,1536})
__global__ __launch_bounds__(256) void gemm_f32(
    const float* __restrict__ A, const float* __restrict__ Bm,
    const float* __restrict__ bias, float* __restrict__ Cm,
    int M, int N, int K, int flags)
{
  __shared__ float As[64][17];
  __shared__ float Bs[16][65];
  const int tid = threadIdx.x;
  const int tx = tid & 15, ty = tid >> 4;
  const int row0 = blockIdx.y * 64, col0 = blockIdx.x * 64;
  float acc[4][4] = {};
  for (int k0 = 0; k0 < K; k0 += 16){
    #pragma unroll
    for (int r = 0; r < 4; r++){
      int l = tid + r*256;
      int m = l >> 4, kk = l & 15;
      int gr = row0 + m;
      As[m][kk] = (gr < M) ? A[(size_t)gr*K + k0 + kk] : 0.0f;
    }
    #pragma unroll
    for (int r = 0; r < 4; r++){
      int l = tid + r*256;
      int n = l & 63, kk = l >> 6;
      Bs[kk][n] = Bm[(size_t)(k0+kk)*N + col0 + n];
    }
    __syncthreads();
    #pragma unroll
    for (int kk = 0; kk < 16; kk++){
      float a[4], b[4];
      #pragma unroll
      for (int i=0;i<4;i++) a[i] = As[ty*4+i][kk];
      #pragma unroll
      for (int j=0;j<4;j++) b[j] = Bs[kk][tx*4+j];
      #pragma unroll
      for (int i=0;i<4;i++)
        #pragma unroll
        for (int j=0;j<4;j++)
          acc[i][j] = fmaf(a[i], b[j], acc[i][j]);
    }
    __syncthreads();
  }
  #pragma unroll
  for (int i=0;i<4;i++){
    int gr = row0 + ty*4 + i;
    if (gr >= M) continue;
    #pragma unroll
    for (int j=0;j<4;j++){
      int gc = col0 + tx*4 + j;
      float v2 = acc[i][j];
      if (flags & 1) v2 += bias[gc];
      if (flags & 2) v2 = gelu_exact(v2);
      Cm[(size_t)gr*N + gc] = v2;
    }
  }
}

// ---------------- Attention: one block per (b,h,i) row ----------------
__global__ __launch_bounds__(256) void attn_kernel(
    const float* __restrict__ q, const float* __restrict__ k,
    const float* __restrict__ v, float* __restrict__ glob)
{
  const int i = blockIdx.x, h = blockIdx.y, b = blockIdx.z;
  const int tid = threadIdx.x, lane = tid & 63, wv = tid >> 6;
  __shared__ float qs[DHD];
  __shared__ float s[NT];
  __shared__ float red[8];
  __shared__ float ored[4][DHD];
  const float* qrow = q + ((size_t)(b*NT + i))*CD + h*DHD;
  if (tid < DHD) qs[tid] = qrow[tid];
  __syncthreads();
  const float* kb = k + (size_t)b*NT*CD + h*DHD;
  float mloc = -1e30f;
  for (int j = tid; j < NT; j += 256){
    const float* kr = kb + (size_t)j*CD;
    float d = 0.0f;
    #pragma unroll
    for (int t = 0; t < DHD; t += 4){
      float4 kv = *reinterpret_cast<const float4*>(kr + t);
      d += qs[t]*kv.x + qs[t+1]*kv.y + qs[t+2]*kv.z + qs[t+3]*kv.w;
    }
    d *= 0.125f;
    s[j] = d;
    mloc = fmaxf(mloc, d);
  }
  #pragma unroll
  for (int o = 32; o > 0; o >>= 1) mloc = fmaxf(mloc, __shfl_xor(mloc, o));
  if (lane == 0) red[wv] = mloc;
  __syncthreads();
  if (tid == 0) red[4] = fmaxf(fmaxf(red[0],red[1]), fmaxf(red[2],red[3]));
  __syncthreads();
  const float m = red[4];
  float lloc = 0.0f;
  for (int j = tid; j < NT; j += 256){
    float e = expf(s[j] - m);
    s[j] = e; lloc += e;
  }
  #pragma unroll
  for (int o = 32; o > 0; o >>= 1) lloc += __shfl_xor(lloc, o);
  if (lane == 0) red[wv] = lloc;
  __syncthreads();
  if (tid == 0) red[5] = red[0]+red[1]+red[2]+red[3];
  __syncthreads();
  const float linv = 1.0f / red[5];
  const float* vb = v + (size_t)b*NT*CD + h*DHD;
  float acc = 0.0f;
  for (int j = wv; j < NT; j += 4)
    acc += s[j] * vb[(size_t)j*CD + lane];
  ored[wv][lane] = acc;
  __syncthreads();
  if (wv == 0){
    float o = (ored[0][lane]+ored[1][lane]+ored[2][lane]+ored[3][lane]) * linv;
    glob[((size_t)(b*NT + i))*CD + h*DHD + lane] = o;
  }
}

// ---------------- Depthwise 3x3 SAME conv on (8,32,32,512) NHWC ----------------
__global__ __launch_bounds__(512) void dwconv(
    const float* __restrict__ x, const float* __restrict__ w, float* __restrict__ out)
{
  const int c = threadIdx.x;
  const int xx = blockIdx.x & 31;
  const int y  = (blockIdx.x >> 5) & 31;
  const int b  = blockIdx.x >> 10;
  float acc = 0.0f;
  #pragma unroll
  for (int ky = 0; ky < 3; ky++){
    int yy = y + ky - 1; if (yy < 0 || yy > 31) continue;
    #pragma unroll
    for (int kx = 0; kx < 3; kx++){
      int x2 = xx + kx - 1; if (x2 < 0 || x2 > 31) continue;
      acc += x[((size_t)(b*NT + 1 + yy*32 + x2))*CD + c] * w[(ky*3+kx)*CD + c];
    }
  }
  out[((size_t)(b*HW + y*32 + xx))*CD + c] = acc;
}

// ---------------- GroupNorm(1) stats: total sum/sumsq per sample ----------------
__global__ __launch_bounds__(512) void gn_stats(const float* __restrict__ mm, float* __restrict__ tot)
{
  const int b = blockIdx.x >> 3, ch = blockIdx.x & 7;
  const int c = threadIdx.x;
  const float* base = mm + ((size_t)b*HW + ch*128)*CD + c;
  float s = 0.0f, s2 = 0.0f;
  for (int r = 0; r < 128; r++){ float v = base[(size_t)r*CD]; s += v; s2 += v*v; }
  #pragma unroll
  for (int o = 32; o > 0; o >>= 1){ s += __shfl_xor(s, o); s2 += __shfl_xor(s2, o); }
  __shared__ float rs[8], rs2[8];
  const int lane = c & 63, wv = c >> 6;
  if (lane == 0){ rs[wv] = s; rs2[wv] = s2; }
  __syncthreads();
  if (c == 0){
    float a = 0, a2 = 0;
    for (int i2 = 0; i2 < 8; i2++){ a += rs[i2]; a2 += rs2[i2]; }
    atomicAdd(&tot[b*2], a); atomicAdd(&tot[b*2+1], a2);
  }
}

__global__ void gn_finalize(const float* __restrict__ tot, float* __restrict__ musr)
{
  const int b = threadIdx.x;
  if (b >= BB) return;
  const float inv = 1.0f / ((float)HW * CD);
  float mu = tot[b*2] * inv;
  float var = tot[b*2+1] * inv - mu*mu;
  musr[b*2] = mu; musr[b*2+1] = rsqrtf(var + 1e-5f);
}

// apply: writes out rows 1..1024 of a (B,1025,512) tensor
__global__ __launch_bounds__(512) void gn_apply(
    const float* __restrict__ mm, const float* __restrict__ musr,
    const float* __restrict__ g, const float* __restrict__ bb,
    float* __restrict__ out, int dogelu)
{
  const int c = threadIdx.x;
  const int p = blockIdx.x & (HW-1);
  const int b = blockIdx.x >> 10;
  const float mu = musr[b*2], rstd = musr[b*2+1];
  float v = mm[((size_t)b*HW + p)*CD + c];
  v = (v - mu) * rstd * g[c] + bb[c];
  if (dogelu) v = gelu_exact(v);
  out[((size_t)(b*NT + 1 + p))*CD + c] = v;
}

// column means over rows 1..1024 -> row 0 (cls token)
__global__ __launch_bounds__(512) void colmean_acc(const float* __restrict__ out, float* __restrict__ colsum)
{
  const int b = blockIdx.x >> 3, ch = blockIdx.x & 7;
  const int c = threadIdx.x;
  const float* base = out + ((size_t)(b*NT) + 1 + ch*128)*CD + c;
  float s = 0.0f;
  for (int r = 0; r < 128; r++) s += base[(size_t)r*CD];
  atomicAdd(&colsum[b*CD + c], s);
}

__global__ __launch_bounds__(512) void colmean_fin(const float* __restrict__ colsum, float* __restrict__ out)
{
  const int c = threadIdx.x, b = blockIdx.x;
  out[((size_t)b*NT)*CD + c] = colsum[b*CD + c] * (1.0f/HW);
}

// ---------------- FFT branch: separable direct DFTs ----------------
// F1: DFT over y.  U[ky,xx] = sum_y x[y,xx] e^{-2pi i ky y/32}
__global__ __launch_bounds__(512) void fft_f1(
    const float* __restrict__ x, float* __restrict__ Ur, float* __restrict__ Ui)
{
  const int c = threadIdx.x;
  const int xx = blockIdx.x & 31;
  const int b = blockIdx.x >> 5;
  __shared__ float ct[32], st[32];
  if (c < 32){ float ang = 6.283185307179586f * c / 32.0f; ct[c] = cosf(ang); st[c] = sinf(ang); }
  __syncthreads();
  float v[32];
  #pragma unroll
  for (int y = 0; y < 32; y++) v[y] = x[((size_t)(b*NT + 1 + y*32 + xx))*CD + c];
  for (int ky = 0; ky < 32; ky++){
    float sr = 0.0f, si = 0.0f;
    #pragma unroll
    for (int y = 0; y < 32; y++){
      int idx = (ky*y) & 31;
      sr += v[y]*ct[idx]; si -= v[y]*st[idx];
    }
    size_t o = ((size_t)((b*32+ky)*32+xx))*CD + c;
    Ur[o] = sr; Ui[o] = si;
  }
}

// F2: rfft over xx (kx=0..16) then filter multiply -> G
__global__ __launch_bounds__(512) void fft_f2(
    const float* __restrict__ Ur, const float* __restrict__ Ui,
    const float* __restrict__ wr, const float* __restrict__ wi,
    float* __restrict__ Gr, float* __restrict__ Gi)
{
  const int c = threadIdx.x;
  const int ky = blockIdx.x & 31;
  const int b = blockIdx.x >> 5;
  __shared__ float ct[32], st[32];
  if (c < 32){ float ang = 6.283185307179586f * c / 32.0f; ct[c] = cosf(ang); st[c] = sinf(ang); }
  __syncthreads();
  float ur[32], ui[32];
  #pragma unroll
  for (int xx = 0; xx < 32; xx++){
    size_t o = ((size_t)((b*32+ky)*32+xx))*CD + c;
    ur[xx] = Ur[o]; ui[xx] = Ui[o];
  }
  for (int kx = 0; kx < FWD; kx++){
    float ar = 0.0f, ai = 0.0f;
    #pragma unroll
    for (int xx = 0; xx < 32; xx++){
      int idx = (kx*xx) & 31;
      float cc = ct[idx], ss = st[idx];
      ar += ur[xx]*cc + ui[xx]*ss;
      ai += ui[xx]*cc - ur[xx]*ss;
    }
    size_t fo = ((size_t)(ky*FWD+kx))*CD + c;
    float fwr = wr[fo], fwi = wi[fo];
    size_t go = ((size_t)((b*32+ky)*FWD+kx))*CD + c;
    Gr[go] = ar*fwr - ai*fwi;
    Gi[go] = ar*fwi + ai*fwr;
  }
}

// F3: ifft over ky (scale 1/32). T[y,kx] = (1/32) sum_ky G[ky,kx] e^{+2pi i ky y/32}
__global__ __launch_bounds__(512) void fft_f3(
    const float* __restrict__ Gr, const float* __restrict__ Gi,
    float* __restrict__ Tr, float* __restrict__ Ti)
{
  const int c = threadIdx.x;
  const int kx = blockIdx.x % FWD;
  const int b = blockIdx.x / FWD;
  __shared__ float ct[32], st[32];
  if (c < 32){ float ang = 6.283185307179586f * c / 32.0f; ct[c] = cosf(ang); st[c] = sinf(ang); }
  __syncthreads();
  float gr[32], gi[32];
  #pragma unroll
  for (int ky = 0; ky < 32; ky++){
    size_t o = ((size_t)((b*32+ky)*FWD+kx))*CD + c;
    gr[ky] = Gr[o]; gi[ky] = Gi[o];
  }
  for (int y = 0; y < 32; y++){
    float tr = 0.0f, ti = 0.0f;
    #pragma unroll
    for (int ky = 0; ky < 32; ky++){
      int idx = (ky*y) & 31;
      float cc = ct[idx], ss = st[idx];
      tr += gr[ky]*cc - gi[ky]*ss;
      ti += gr[ky]*ss + gi[ky]*cc;
    }
    size_t o = ((size_t)((b*32+y)*FWD+kx))*CD + c;
    Tr[o] = tr*(1.0f/32.0f); Ti[o] = ti*(1.0f/32.0f);
  }
}

// F4: irfft over kx (scale 1/32), Hermitian-half reconstruction
__global__ __launch_bounds__(512) void fft_f4(
    const float* __restrict__ Tr, const float* __restrict__ Ti, float* __restrict__ xe)
{
  const int c = threadIdx.x;
  const int y = blockIdx.x & 31;
  const int b = blockIdx.x >> 5;
  __shared__ float ct[32], st[32];
  if (c < 32){ float ang = 6.283185307179586f * c / 32.0f; ct[c] = cosf(ang); st[c] = sinf(ang); }
  __syncthreads();
  float tr[FWD], ti[FWD];
  #pragma unroll
  for (int kx = 0; kx < FWD; kx++){
    size_t o = ((size_t)((b*32+y)*FWD+kx))*CD + c;
    tr[kx] = Tr[o]; ti[kx] = Ti[o];
  }
  for (int x2 = 0; x2 < 32; x2++){
    float acc = tr[0] + ((x2 & 1) ? -tr[16] : tr[16]);
    #pragma unroll
    for (int k2 = 1; k2 < 16; k2++){
      int idx = (k2*x2) & 31;
      acc += 2.0f*(tr[k2]*ct[idx] - ti[k2]*st[idx]);
    }
    xe[((size_t)((b*32+y)*32+x2))*CD + c] = acc*(1.0f/32.0f);
  }
}

// ---------------- gate: concat build, gate MLP tail + fusion ----------------
__global__ __launch_bounds__(512) void catbuild(
    const float* __restrict__ glob, const float* __restrict__ loc,
    const float* __restrict__ fr, float* __restrict__ cat)
{
  size_t idx = (size_t)blockIdx.x*512 + threadIdx.x;
  if (idx >= (size_t)BB*NT*1536) return;
  size_t token = idx / 1536;
  int c = (int)(idx % 1536);
  const float* src = (c < 512) ? glob : (c < 1024 ? loc : fr);
  cat[idx] = src[token*CD + (c & 511)];
}

__global__ __launch_bounds__(512) void gate_fuse(
    const float* __restrict__ h1, const float* __restrict__ gW2, const float* __restrict__ gb2,
    const float* __restrict__ glob, const float* __restrict__ loc, const float* __restrict__ fr,
    float* __restrict__ fused)
{
  const int token = blockIdx.x;
  const int tid = threadIdx.x;
  __shared__ float r0[512], r1[512], r2[512];
  float p0 = 0, p1 = 0, p2 = 0;
  if (tid < 384){
    float h = h1[(size_t)token*384 + tid];
    p0 = h * gW2[tid*3+0]; p1 = h * gW2[tid*3+1]; p2 = h * gW2[tid*3+2];
  }
  r0[tid] = p0; r1[tid] = p1; r2[tid] = p2;
  __syncthreads();
  for (int s2 = 256; s2 > 0; s2 >>= 1){
    if (tid < s2){ r0[tid] += r0[tid+s2]; r1[tid] += r1[tid+s2]; r2[tid] += r2[tid+s2]; }
    __syncthreads();
  }
  __shared__ float gw[3];
  if (tid == 0){
    float l0 = r0[0] + gb2[0], l1 = r1[0] + gb2[1], l2 = r2[0] + gb2[2];
    float mx = fmaxf(l0, fmaxf(l1, l2));
    float e0 = expf(l0-mx), e1 = expf(l1-mx), e2 = expf(l2-mx);
    float inv = 1.0f/(e0+e1+e2);
    gw[0] = e0*inv; gw[1] = e1*inv; gw[2] = e2*inv;
  }
  __syncthreads();
  size_t o = (size_t)token*CD + tid;
  fused[o] = gw[0]*glob[o] + gw[1]*loc[o] + gw[2]*fr[o];
}

extern "C" void kernel_launch(void* const* d_in, const int* in_sizes, int n_in,
                              void* d_out, int out_size, void* d_ws, size_t ws_size,
                              hipStream_t stream)
{
  const float* x     = (const float*)d_in[0];
  const float* Wq    = (const float*)d_in[1];
  const float* Wk    = (const float*)d_in[2];
  const float* Wv    = (const float*)d_in[3];
  const float* dw_w  = (const float*)d_in[4];
  const float* pw_w  = (const float*)d_in[5];
  const float* ln_g  = (const float*)d_in[6];
  const float* ln_b  = (const float*)d_in[7];
  const float* fr_wr = (const float*)d_in[8];
  const float* fr_wi = (const float*)d_in[9];
  const float* fr_pw = (const float*)d_in[10];
  const float* fr_g  = (const float*)d_in[11];
  const float* fr_b  = (const float*)d_in[12];
  const float* g_W1  = (const float*)d_in[13];
  const float* g_b1  = (const float*)d_in[14];
  const float* g_W2  = (const float*)d_in[15];
  const float* g_b2  = (const float*)d_in[16];
  const float* Wp    = (const float*)d_in[17];
  const float* bp    = (const float*)d_in[18];

  float* ws = (float*)d_ws;
  const size_t SZ_TOK = (size_t)BB*NT*CD;          // 4,198,400
  float* q    = ws;
  float* k    = ws + SZ_TOK;
  float* v    = ws + 2*SZ_TOK;
  float* cat  = ws;                                 // overlays q,k,v (dead after attn)
  float* glob = ws + 3*SZ_TOK;
  float* loc  = ws + 4*SZ_TOK;
  float* fr   = ws + 5*SZ_TOK;
  float* scrA = ws + 6*SZ_TOK;                      // 8,388,608 floats
  float* scrB = scrA + 8388608;                     // 4,456,448 floats
  float* stats = scrB + 4456448;
  float* tot    = stats;        // 16
  float* musr   = stats + 16;   // 16
  float* colsum = stats + 64;   // 4096

  const int M_TOK = BB*NT;  // 8200
  auto gemmGrid = [](int M, int N){ return dim3((unsigned)((N+63)/64), (unsigned)((M+63)/64)); };

  // ---- branch 1: QKV + attention ----
  gemm_f32<<<gemmGrid(M_TOK,512), 256, 0, stream>>>(x, Wq, nullptr, q, M_TOK, 512, 512, 0);
  gemm_f32<<<gemmGrid(M_TOK,512), 256, 0, stream>>>(x, Wk, nullptr, k, M_TOK, 512, 512, 0);
  gemm_f32<<<gemmGrid(M_TOK,512), 256, 0, stream>>>(x, Wv, nullptr, v, M_TOK, 512, 512, 0);
  attn_kernel<<<dim3(NT, NH, BB), 256, 0, stream>>>(q, k, v, glob);

  // ---- branch 2: dw conv -> pw -> GroupNorm -> cls ----
  dwconv<<<BB*HW, 512, 0, stream>>>(x, dw_w, scrA);
  gemm_f32<<<gemmGrid(BB*HW,512), 256, 0, stream>>>(scrA, pw_w, nullptr, scrB, BB*HW, 512, 512, 0);
  hipMemsetAsync(tot, 0, 16*sizeof(float), stream);
  gn_stats<<<BB*8, 512, 0, stream>>>(scrB, tot);
  gn_finalize<<<1, 64, 0, stream>>>(tot, musr);
  gn_apply<<<BB*HW, 512, 0, stream>>>(scrB, musr, ln_g, ln_b, loc, 0);
  hipMemsetAsync(colsum, 0, 4096*sizeof(float), stream);
  colmean_acc<<<BB*8, 512, 0, stream>>>(loc, colsum);
  colmean_fin<<<BB, 512, 0, stream>>>(colsum, loc);

  // ---- branch 3: FFT filter -> pw -> GroupNorm -> GELU -> cls ----
  float* Ur = scrA;            float* Ui = scrA + 4194304;
  float* Gr = scrB;            float* Gi = scrB + 2228224;
  float* Tr = scrA;            float* Ti = scrA + 2228224;
  float* xe = scrB;
  fft_f1<<<BB*32, 512, 0, stream>>>(x, Ur, Ui);
  fft_f2<<<BB*32, 512, 0, stream>>>(Ur, Ui, fr_wr, fr_wi, Gr, Gi);
  fft_f3<<<BB*FWD, 512, 0, stream>>>(Gr, Gi, Tr, Ti);
  fft_f4<<<BB*32, 512, 0, stream>>>(Tr, Ti, xe);
  gemm_f32<<<gemmGrid(BB*HW,512), 256, 0, stream>>>(xe, fr_pw, nullptr, scrA, BB*HW, 512, 512, 0);
  hipMemsetAsync(tot, 0, 16*sizeof(float), stream);
  gn_stats<<<BB*8, 512, 0, stream>>>(scrA, tot);
  gn_finalize<<<1, 64, 0, stream>>>(tot, musr);
  gn_apply<<<BB*HW, 512, 0, stream>>>(scrA, musr, fr_g, fr_b, fr, 1);
  hipMemsetAsync(colsum, 0, 4096*sizeof(float), stream);
  colmean_acc<<<BB*8, 512, 0, stream>>>(fr, colsum);
  colmean_fin<<<BB, 512, 0, stream>>>(colsum, fr);

  // ---- gate MLP + fusion + output projection ----
  size_t cat_total = (size_t)M_TOK*1536;
  catbuild<<<(unsigned)((cat_total + 511)/512), 512, 0, stream>>>(glob, loc, fr, cat);
  gemm_f32<<<gemmGrid(M_TOK,384), 256, 0, stream>>>(cat, g_W1, g_b1, scrA, M_TOK, 384, 1536, 3);
  gate_fuse<<<M_TOK, 512, 0, stream>>>(scrA, g_W2, g_b2, glob, loc, fr, scrB);
  gemm_f32<<<gemmGrid(M_TOK,512), 256, 0, stream>>>(scrB, Wp, bp, (float*)d_out, M_TOK, 512, 512, 1);
}

// Round 2
// 1304.158 us; speedup vs baseline: 3.9438x; 3.9438x over previous
//
#include <hip/hip_runtime.h>
#include <math.h>

#define BB 8
#define NT 1025
#define CD 512
#define NH 8
#define DHD 64
#define HW 1024
#define GS 32
#define FWD 17

typedef __attribute__((ext_vector_type(8))) short short8;
typedef __attribute__((ext_vector_type(4))) float f32x4;

__device__ __forceinline__ float gelu_exact(float x){
  return 0.5f * x * (1.0f + erff(x * 0.70710678118654752f));
}

__device__ __forceinline__ short f2bf(float f){
  unsigned u = __float_as_uint(f);
  unsigned r = (u + 0x7FFFu + ((u >> 16) & 1u)) >> 16;
  return (short)r;
}

// ---------------- GEMM: C[M,N] = A[M,K] @ B[K,N] (+bias, +gelu, +bf16 store) ----
// flags: 1=bias, 2=gelu, 4=store bf16
__global__ __launch_bounds__(256) void gemm_f32(
    const float* __restrict__ A, const float* __restrict__ Bm,
    const float* __restrict__ bias, float* __restrict__ Cm,
    int M, int N, int K, int flags)
{
  __shared__ float As[64][17];
  __shared__ float Bs[16][65];
  const int tid = threadIdx.x;
  const int tx = tid & 15, ty = tid >> 4;
  const int row0 = blockIdx.y * 64, col0 = blockIdx.x * 64;
  float acc[4][4] = {};
  for (int k0 = 0; k0 < K; k0 += 16){
    #pragma unroll
    for (int r = 0; r < 4; r++){
      int l = tid + r*256;
      int m = l >> 4, kk = l & 15;
      int gr = row0 + m;
      As[m][kk] = (gr < M) ? A[(size_t)gr*K + k0 + kk] : 0.0f;
    }
    #pragma unroll
    for (int r = 0; r < 4; r++){
      int l = tid + r*256;
      int n = l & 63, kk = l >> 6;
      Bs[kk][n] = Bm[(size_t)(k0+kk)*N + col0 + n];
    }
    __syncthreads();
    #pragma unroll
    for (int kk = 0; kk < 16; kk++){
      float a[4], b[4];
      #pragma unroll
      for (int i=0;i<4;i++) a[i] = As[ty*4+i][kk];
      #pragma unroll
      for (int j=0;j<4;j++) b[j] = Bs[kk][tx*4+j];
      #pragma unroll
      for (int i=0;i<4;i++)
        #pragma unroll
        for (int j=0;j<4;j++)
          acc[i][j] = fmaf(a[i], b[j], acc[i][j]);
    }
    __syncthreads();
  }
  #pragma unroll
  for (int i=0;i<4;i++){
    int gr = row0 + ty*4 + i;
    if (gr >= M) continue;
    #pragma unroll
    for (int j=0;j<4;j++){
      int gc = col0 + tx*4 + j;
      float v2 = acc[i][j];
      if (flags & 1) v2 += bias[gc];
      if (flags & 2) v2 = gelu_exact(v2);
      if (flags & 4) ((short*)Cm)[(size_t)gr*N + gc] = f2bf(v2);
      else           Cm[(size_t)gr*N + gc] = v2;
    }
  }
}

// ---------------- Flash attention, bf16 MFMA 16x16x32 ----------------
// grid: (17 q-tiles, NH, BB); 256 threads = 4 waves; wave owns 16 q rows.
__global__ __launch_bounds__(256) void attn_mfma(
    const short* __restrict__ qb, const short* __restrict__ kb,
    const short* __restrict__ vb, float* __restrict__ glob)
{
  const int qt = blockIdx.x, h = blockIdx.y, b = blockIdx.z;
  const int tid = threadIdx.x;
  const int lane = tid & 63, wv = tid >> 6;
  const int lc = lane & 15;      // column index within 16-tile
  const int lg = lane >> 4;      // lane group 0..3
  const int bN = b * NT;
  const int q0w = qt*64 + wv*16; // this wave's first q row (within sample)

  __shared__ short Plds[4][16][72];   // per-wave P tile, padded rows
  __shared__ short Vt[64][72];        // V^T tile (d x key), padded

  // Q fragments (resident): A-layout row=lc, k = lg*8+j (+32 for second frag)
  short8 qf0, qf1;
  {
    const short* qbase = qb + (size_t)(bN + q0w + lc)*CD + h*DHD + lg*8;
    qf0 = *(const short8*)(qbase);
    qf1 = *(const short8*)(qbase + 32);
  }

  float m_old[4], l_sum[4];
  f32x4 o_acc[4];
  #pragma unroll
  for (int e=0;e<4;e++){ m_old[e] = -1e30f; l_sum[e] = 0.0f;
    o_acc[e] = (f32x4){0.f,0.f,0.f,0.f}; }

  for (int kt = 0; kt < 17; kt++){
    const int kt0 = kt*64;
    __syncthreads();
    // ---- stage V^T (64 keys x 64 dims), zero invalid keys ----
    {
      int key = tid & 63, dg = tid >> 6;
      bool valid = (kt0 + key) < NT;
      short8 a0 = {0,0,0,0,0,0,0,0}, a1 = {0,0,0,0,0,0,0,0};
      if (valid){
        const short* vrow = vb + (size_t)(bN + kt0 + key)*CD + h*DHD + dg*16;
        a0 = ((const short8*)vrow)[0];
        a1 = ((const short8*)vrow)[1];
      }
      #pragma unroll
      for (int i=0;i<8;i++){ Vt[dg*16 + i][key] = a0[i]; Vt[dg*16 + 8 + i][key] = a1[i]; }
    }
    __syncthreads();

    // ---- QK^T: 4 col tiles of 16 keys ----
    f32x4 s[4];
    #pragma unroll
    for (int ct=0; ct<4; ct++){
      const short* kbase = kb + (size_t)(bN + kt0 + ct*16 + lc)*CD + h*DHD + lg*8;
      short8 kf0 = *(const short8*)(kbase);
      short8 kf1 = *(const short8*)(kbase + 32);
      f32x4 z = {0.f,0.f,0.f,0.f};
      s[ct] = __builtin_amdgcn_mfma_f32_16x16x32_bf16(qf0, kf0, z, 0,0,0);
      s[ct] = __builtin_amdgcn_mfma_f32_16x16x32_bf16(qf1, kf1, s[ct], 0,0,0);
    }
    // scale + mask invalid keys
    #pragma unroll
    for (int ct=0; ct<4; ct++){
      bool kvalid = (kt0 + ct*16 + lc) < NT;
      #pragma unroll
      for (int e=0;e<4;e++) s[ct][e] = kvalid ? s[ct][e]*0.125f : -1e30f;
    }
    // row max (per reg e = row lg*4+e), reduce across the 16-lane column group
    float rm[4];
    #pragma unroll
    for (int e=0;e<4;e++)
      rm[e] = fmaxf(fmaxf(s[0][e],s[1][e]), fmaxf(s[2][e],s[3][e]));
    #pragma unroll
    for (int msk=1; msk<16; msk<<=1)
      #pragma unroll
      for (int e=0;e<4;e++) rm[e] = fmaxf(rm[e], __shfl_xor(rm[e], msk));
    float mn[4], sc[4];
    #pragma unroll
    for (int e=0;e<4;e++){ mn[e] = fmaxf(m_old[e], rm[e]); sc[e] = expf(m_old[e]-mn[e]); m_old[e]=mn[e]; }
    // P = exp(s-mn), row sums
    float rs[4] = {0.f,0.f,0.f,0.f};
    #pragma unroll
    for (int ct=0; ct<4; ct++)
      #pragma unroll
      for (int e=0;e<4;e++){ float p = expf(s[ct][e]-mn[e]); s[ct][e]=p; rs[e]+=p; }
    #pragma unroll
    for (int msk=1; msk<16; msk<<=1)
      #pragma unroll
      for (int e=0;e<4;e++) rs[e] += __shfl_xor(rs[e], msk);
    #pragma unroll
    for (int e=0;e<4;e++) l_sum[e] = l_sum[e]*sc[e] + rs[e];
    #pragma unroll
    for (int dt=0; dt<4; dt++)
      #pragma unroll
      for (int e=0;e<4;e++) o_acc[dt][e] *= sc[e];
    // write P (bf16) to per-wave LDS: row = lg*4+e, col = ct*16+lc
    #pragma unroll
    for (int ct=0; ct<4; ct++)
      #pragma unroll
      for (int e=0;e<4;e++) Plds[wv][lg*4+e][ct*16+lc] = f2bf(s[ct][e]);
    __syncthreads();

    // ---- PV: O += P(16x64) * V(64x64) ----
    #pragma unroll
    for (int ks=0; ks<2; ks++){
      short8 pa = *(const short8*)&Plds[wv][lc][ks*32 + lg*8];
      #pragma unroll
      for (int dt=0; dt<4; dt++){
        short8 vf = *(const short8*)&Vt[dt*16 + lc][ks*32 + lg*8];
        o_acc[dt] = __builtin_amdgcn_mfma_f32_16x16x32_bf16(pa, vf, o_acc[dt], 0,0,0);
      }
    }
  }

  // ---- finalize + store (fp32) ----
  #pragma unroll
  for (int e=0;e<4;e++){
    int q = q0w + lg*4 + e;
    if (q >= NT) continue;
    float inv = 1.0f / l_sum[e];
    #pragma unroll
    for (int dt=0; dt<4; dt++)
      glob[(size_t)(bN + q)*CD + h*DHD + dt*16 + lc] = o_acc[dt][e] * inv;
  }
}

// ---------------- Depthwise 3x3 SAME conv on (8,32,32,512) NHWC ----------------
__global__ __launch_bounds__(512) void dwconv(
    const float* __restrict__ x, const float* __restrict__ w, float* __restrict__ out)
{
  const int c = threadIdx.x;
  const int xx = blockIdx.x & 31;
  const int y  = (blockIdx.x >> 5) & 31;
  const int b  = blockIdx.x >> 10;
  float acc = 0.0f;
  #pragma unroll
  for (int ky = 0; ky < 3; ky++){
    int yy = y + ky - 1; if (yy < 0 || yy > 31) continue;
    #pragma unroll
    for (int kx = 0; kx < 3; kx++){
      int x2 = xx + kx - 1; if (x2 < 0 || x2 > 31) continue;
      acc += x[((size_t)(b*NT + 1 + yy*32 + x2))*CD + c] * w[(ky*3+kx)*CD + c];
    }
  }
  out[((size_t)(b*HW + y*32 + xx))*CD + c] = acc;
}

// ---------------- GroupNorm(1) stats ----------------
__global__ __launch_bounds__(512) void gn_stats(const float* __restrict__ mm, float* __restrict__ tot)
{
  const int b = blockIdx.x >> 3, ch = blockIdx.x & 7;
  const int c = threadIdx.x;
  const float* base = mm + ((size_t)b*HW + ch*128)*CD + c;
  float s = 0.0f, s2 = 0.0f;
  for (int r = 0; r < 128; r++){ float v = base[(size_t)r*CD]; s += v; s2 += v*v; }
  #pragma unroll
  for (int o = 32; o > 0; o >>= 1){ s += __shfl_xor(s, o); s2 += __shfl_xor(s2, o); }
  __shared__ float rs[8], rs2[8];
  const int lane = c & 63, wv = c >> 6;
  if (lane == 0){ rs[wv] = s; rs2[wv] = s2; }
  __syncthreads();
  if (c == 0){
    float a = 0, a2 = 0;
    for (int i2 = 0; i2 < 8; i2++){ a += rs[i2]; a2 += rs2[i2]; }
    atomicAdd(&tot[b*2], a); atomicAdd(&tot[b*2+1], a2);
  }
}

__global__ void gn_finalize(const float* __restrict__ tot, float* __restrict__ musr)
{
  const int b = threadIdx.x;
  if (b >= BB) return;
  const float inv = 1.0f / ((float)HW * CD);
  float mu = tot[b*2] * inv;
  float var = tot[b*2+1] * inv - mu*mu;
  musr[b*2] = mu; musr[b*2+1] = rsqrtf(var + 1e-5f);
}

__global__ __launch_bounds__(512) void gn_apply(
    const float* __restrict__ mm, const float* __restrict__ musr,
    const float* __restrict__ g, const float* __restrict__ bb,
    float* __restrict__ out, int dogelu)
{
  const int c = threadIdx.x;
  const int p = blockIdx.x & (HW-1);
  const int b = blockIdx.x >> 10;
  const float mu = musr[b*2], rstd = musr[b*2+1];
  float v = mm[((size_t)b*HW + p)*CD + c];
  v = (v - mu) * rstd * g[c] + bb[c];
  if (dogelu) v = gelu_exact(v);
  out[((size_t)(b*NT + 1 + p))*CD + c] = v;
}

__global__ __launch_bounds__(512) void colmean_acc(const float* __restrict__ out, float* __restrict__ colsum)
{
  const int b = blockIdx.x >> 3, ch = blockIdx.x & 7;
  const int c = threadIdx.x;
  const float* base = out + ((size_t)(b*NT) + 1 + ch*128)*CD + c;
  float s = 0.0f;
  for (int r = 0; r < 128; r++) s += base[(size_t)r*CD];
  atomicAdd(&colsum[b*CD + c], s);
}

__global__ __launch_bounds__(512) void colmean_fin(const float* __restrict__ colsum, float* __restrict__ out)
{
  const int c = threadIdx.x, b = blockIdx.x;
  out[((size_t)b*NT)*CD + c] = colsum[b*CD + c] * (1.0f/HW);
}

// ---------------- FFT branch: separable direct DFTs ----------------
__global__ __launch_bounds__(512) void fft_f1(
    const float* __restrict__ x, float* __restrict__ Ur, float* __restrict__ Ui)
{
  const int c = threadIdx.x;
  const int xx = blockIdx.x & 31;
  const int b = blockIdx.x >> 5;
  __shared__ float ct[32], st[32];
  if (c < 32){ float ang = 6.283185307179586f * c / 32.0f; ct[c] = cosf(ang); st[c] = sinf(ang); }
  __syncthreads();
  float v[32];
  #pragma unroll
  for (int y = 0; y < 32; y++) v[y] = x[((size_t)(b*NT + 1 + y*32 + xx))*CD + c];
  for (int ky = 0; ky < 32; ky++){
    float sr = 0.0f, si = 0.0f;
    #pragma unroll
    for (int y = 0; y < 32; y++){
      int idx = (ky*y) & 31;
      sr += v[y]*ct[idx]; si -= v[y]*st[idx];
    }
    size_t o = ((size_t)((b*32+ky)*32+xx))*CD + c;
    Ur[o] = sr; Ui[o] = si;
  }
}

__global__ __launch_bounds__(512) void fft_f2(
    const float* __restrict__ Ur, const float* __restrict__ Ui,
    const float* __restrict__ wr, const float* __restrict__ wi,
    float* __restrict__ Gr, float* __restrict__ Gi)
{
  const int c = threadIdx.x;
  const int ky = blockIdx.x & 31;
  const int b = blockIdx.x >> 5;
  __shared__ float ct[32], st[32];
  if (c < 32){ float ang = 6.283185307179586f * c / 32.0f; ct[c] = cosf(ang); st[c] = sinf(ang); }
  __syncthreads();
  float ur[32], ui[32];
  #pragma unroll
  for (int xx = 0; xx < 32; xx++){
    size_t o = ((size_t)((b*32+ky)*32+xx))*CD + c;
    ur[xx] = Ur[o]; ui[xx] = Ui[o];
  }
  for (int kx = 0; kx < FWD; kx++){
    float ar = 0.0f, ai = 0.0f;
    #pragma unroll
    for (int xx = 0; xx < 32; xx++){
      int idx = (kx*xx) & 31;
      float cc = ct[idx], ss = st[idx];
      ar += ur[xx]*cc + ui[xx]*ss;
      ai += ui[xx]*cc - ur[xx]*ss;
    }
    size_t fo = ((size_t)(ky*FWD+kx))*CD + c;
    float fwr = wr[fo], fwi = wi[fo];
    size_t go = ((size_t)((b*32+ky)*FWD+kx))*CD + c;
    Gr[go] = ar*fwr - ai*fwi;
    Gi[go] = ar*fwi + ai*fwr;
  }
}

__global__ __launch_bounds__(512) void fft_f3(
    const float* __restrict__ Gr, const float* __restrict__ Gi,
    float* __restrict__ Tr, float* __restrict__ Ti)
{
  const int c = threadIdx.x;
  const int kx = blockIdx.x % FWD;
  const int b = blockIdx.x / FWD;
  __shared__ float ct[32], st[32];
  if (c < 32){ float ang = 6.283185307179586f * c / 32.0f; ct[c] = cosf(ang); st[c] = sinf(ang); }
  __syncthreads();
  float gr[32], gi[32];
  #pragma unroll
  for (int ky = 0; ky < 32; ky++){
    size_t o = ((size_t)((b*32+ky)*FWD+kx))*CD + c;
    gr[ky] = Gr[o]; gi[ky] = Gi[o];
  }
  for (int y = 0; y < 32; y++){
    float tr = 0.0f, ti = 0.0f;
    #pragma unroll
    for (int ky = 0; ky < 32; ky++){
      int idx = (ky*y) & 31;
      float cc = ct[idx], ss = st[idx];
      tr += gr[ky]*cc - gi[ky]*ss;
      ti += gr[ky]*ss + gi[ky]*cc;
    }
    size_t o = ((size_t)((b*32+y)*FWD+kx))*CD + c;
    Tr[o] = tr*(1.0f/32.0f); Ti[o] = ti*(1.0f/32.0f);
  }
}

__global__ __launch_bounds__(512) void fft_f4(
    const float* __restrict__ Tr, const float* __restrict__ Ti, float* __restrict__ xe)
{
  const int c = threadIdx.x;
  const int y = blockIdx.x & 31;
  const int b = blockIdx.x >> 5;
  __shared__ float ct[32], st[32];
  if (c < 32){ float ang = 6.283185307179586f * c / 32.0f; ct[c] = cosf(ang); st[c] = sinf(ang); }
  __syncthreads();
  float tr[FWD], ti[FWD];
  #pragma unroll
  for (int kx = 0; kx < FWD; kx++){
    size_t o = ((size_t)((b*32+y)*FWD+kx))*CD + c;
    tr[kx] = Tr[o]; ti[kx] = Ti[o];
  }
  for (int x2 = 0; x2 < 32; x2++){
    float acc = tr[0] + ((x2 & 1) ? -tr[16] : tr[16]);
    #pragma unroll
    for (int k2 = 1; k2 < 16; k2++){
      int idx = (k2*x2) & 31;
      acc += 2.0f*(tr[k2]*ct[idx] - ti[k2]*st[idx]);
    }
    xe[((size_t)((b*32+y)*32+x2))*CD + c] = acc*(1.0f/32.0f);
  }
}

// ---------------- gate: concat build, gate MLP tail + fusion ----------------
__global__ __launch_bounds__(512) void catbuild(
    const float* __restrict__ glob, const float* __restrict__ loc,
    const float* __restrict__ fr, float* __restrict__ cat)
{
  size_t idx = (size_t)blockIdx.x*512 + threadIdx.x;
  if (idx >= (size_t)BB*NT*1536) return;
  size_t token = idx / 1536;
  int c = (int)(idx % 1536);
  const float* src = (c < 512) ? glob : (c < 1024 ? loc : fr);
  cat[idx] = src[token*CD + (c & 511)];
}

__global__ __launch_bounds__(512) void gate_fuse(
    const float* __restrict__ h1, const float* __restrict__ gW2, const float* __restrict__ gb2,
    const float* __restrict__ glob, const float* __restrict__ loc, const float* __restrict__ fr,
    float* __restrict__ fused)
{
  const int token = blockIdx.x;
  const int tid = threadIdx.x;
  __shared__ float r0[512], r1[512], r2[512];
  float p0 = 0, p1 = 0, p2 = 0;
  if (tid < 384){
    float h = h1[(size_t)token*384 + tid];
    p0 = h * gW2[tid*3+0]; p1 = h * gW2[tid*3+1]; p2 = h * gW2[tid*3+2];
  }
  r0[tid] = p0; r1[tid] = p1; r2[tid] = p2;
  __syncthreads();
  for (int s2 = 256; s2 > 0; s2 >>= 1){
    if (tid < s2){ r0[tid] += r0[tid+s2]; r1[tid] += r1[tid+s2]; r2[tid] += r2[tid+s2]; }
    __syncthreads();
  }
  __shared__ float gw[3];
  if (tid == 0){
    float l0 = r0[0] + gb2[0], l1 = r1[0] + gb2[1], l2 = r2[0] + gb2[2];
    float mx = fmaxf(l0, fmaxf(l1, l2));
    float e0 = expf(l0-mx), e1 = expf(l1-mx), e2 = expf(l2-mx);
    float inv = 1.0f/(e0+e1+e2);
    gw[0] = e0*inv; gw[1] = e1*inv; gw[2] = e2*inv;
  }
  __syncthreads();
  size_t o = (size_t)token*CD + tid;
  fused[o] = gw[0]*glob[o] + gw[1]*loc[o] + gw[2]*fr[o];
}

extern "C" void kernel_launch(void* const* d_in, const int* in_sizes, int n_in,
                              void* d_out, int out_size, void* d_ws, size_t ws_size,
                              hipStream_t stream)
{
  const float* x     = (const float*)d_in[0];
  const float* Wq    = (const float*)d_in[1];
  const float* Wk    = (const float*)d_in[2];
  const float* Wv    = (const float*)d_in[3];
  const float* dw_w  = (const float*)d_in[4];
  const float* pw_w  = (const float*)d_in[5];
  const float* ln_g  = (const float*)d_in[6];
  const float* ln_b  = (const float*)d_in[7];
  const float* fr_wr = (const float*)d_in[8];
  const float* fr_wi = (const float*)d_in[9];
  const float* fr_pw = (const float*)d_in[10];
  const float* fr_g  = (const float*)d_in[11];
  const float* fr_b  = (const float*)d_in[12];
  const float* g_W1  = (const float*)d_in[13];
  const float* g_b1  = (const float*)d_in[14];
  const float* g_W2  = (const float*)d_in[15];
  const float* g_b2  = (const float*)d_in[16];
  const float* Wp    = (const float*)d_in[17];
  const float* bp    = (const float*)d_in[18];

  float* ws = (float*)d_ws;
  const size_t SZ_TOK = (size_t)BB*NT*CD;          // 4,198,400
  float* glob = ws;
  float* loc  = ws + SZ_TOK;
  float* fr   = ws + 2*SZ_TOK;
  float* cat  = ws + 3*SZ_TOK;                     // 12,595,200 floats
  // bf16 q/k/v overlay the cat region (dead before catbuild)
  const size_t QROWS = 8320;                       // 8200 rounded up (tile overread pad)
  const size_t QSZ   = QROWS * CD;                 // bf16 elements
  short* qb = (short*)cat;
  short* kb = qb + QSZ;
  short* vb = kb + QSZ;
  float* scrA = ws + 6*SZ_TOK;                     // 8,388,608 floats
  float* scrB = scrA + 8388608;                    // 4,456,448 floats
  float* stats = scrB + 4456448;
  float* tot    = stats;        // 16
  float* musr   = stats + 16;   // 16
  float* colsum = stats + 64;   // 4096

  const int M_TOK = BB*NT;  // 8200
  auto gemmGrid = [](int M, int N){ return dim3((unsigned)((N+63)/64), (unsigned)((M+63)/64)); };

  // ---- branch 1: QKV (bf16 out) + MFMA flash attention ----
  gemm_f32<<<gemmGrid(M_TOK,512), 256, 0, stream>>>(x, Wq, nullptr, (float*)qb, M_TOK, 512, 512, 4);
  gemm_f32<<<gemmGrid(M_TOK,512), 256, 0, stream>>>(x, Wk, nullptr, (float*)kb, M_TOK, 512, 512, 4);
  gemm_f32<<<gemmGrid(M_TOK,512), 256, 0, stream>>>(x, Wv, nullptr, (float*)vb, M_TOK, 512, 512, 4);
  attn_mfma<<<dim3(17, NH, BB), 256, 0, stream>>>(qb, kb, vb, glob);

  // ---- branch 2: dw conv -> pw -> GroupNorm -> cls ----
  dwconv<<<BB*HW, 512, 0, stream>>>(x, dw_w, scrA);
  gemm_f32<<<gemmGrid(BB*HW,512), 256, 0, stream>>>(scrA, pw_w, nullptr, scrB, BB*HW, 512, 512, 0);
  hipMemsetAsync(tot, 0, 16*sizeof(float), stream);
  gn_stats<<<BB*8, 512, 0, stream>>>(scrB, tot);
  gn_finalize<<<1, 64, 0, stream>>>(tot, musr);
  gn_apply<<<BB*HW, 512, 0, stream>>>(scrB, musr, ln_g, ln_b, loc, 0);
  hipMemsetAsync(colsum, 0, 4096*sizeof(float), stream);
  colmean_acc<<<BB*8, 512, 0, stream>>>(loc, colsum);
  colmean_fin<<<BB, 512, 0, stream>>>(colsum, loc);

  // ---- branch 3: FFT filter -> pw -> GroupNorm -> GELU -> cls ----
  float* Ur = scrA;            float* Ui = scrA + 4194304;
  float* Gr = scrB;            float* Gi = scrB + 2228224;
  float* Tr = scrA;            float* Ti = scrA + 2228224;
  float* xe = scrB;
  fft_f1<<<BB*32, 512, 0, stream>>>(x, Ur, Ui);
  fft_f2<<<BB*32, 512, 0, stream>>>(Ur, Ui, fr_wr, fr_wi, Gr, Gi);
  fft_f3<<<BB*FWD, 512, 0, stream>>>(Gr, Gi, Tr, Ti);
  fft_f4<<<BB*32, 512, 0, stream>>>(Tr, Ti, xe);
  gemm_f32<<<gemmGrid(BB*HW,512), 256, 0, stream>>>(xe, fr_pw, nullptr, scrA, BB*HW, 512, 512, 0);
  hipMemsetAsync(tot, 0, 16*sizeof(float), stream);
  gn_stats<<<BB*8, 512, 0, stream>>>(scrA, tot);
  gn_finalize<<<1, 64, 0, stream>>>(tot, musr);
  gn_apply<<<BB*HW, 512, 0, stream>>>(scrA, musr, fr_g, fr_b, fr, 1);
  hipMemsetAsync(colsum, 0, 4096*sizeof(float), stream);
  colmean_acc<<<BB*8, 512, 0, stream>>>(fr, colsum);
  colmean_fin<<<BB, 512, 0, stream>>>(colsum, fr);

  // ---- gate MLP + fusion + output projection ----
  size_t cat_total = (size_t)M_TOK*1536;
  catbuild<<<(unsigned)((cat_total + 511)/512), 512, 0, stream>>>(glob, loc, fr, cat);
  gemm_f32<<<gemmGrid(M_TOK,384), 256, 0, stream>>>(cat, g_W1, g_b1, scrA, M_TOK, 384, 1536, 3);
  gate_fuse<<<M_TOK, 512, 0, stream>>>(scrA, g_W2, g_b2, glob, loc, fr, scrB);
  gemm_f32<<<gemmGrid(M_TOK,512), 256, 0, stream>>>(scrB, Wp, bp, (float*)d_out, M_TOK, 512, 512, 1);
}

// Round 3
// 521.053 us; speedup vs baseline: 9.8710x; 2.5029x over previous
//
#include <hip/hip_runtime.h>
#include <math.h>

#define BB 8
#define NT 1025
#define CD 512
#define NH 8
#define DHD 64
#define HW 1024
#define FWD 17
#define MTOK 8200
#define MPAD 8320
#define QKS 1536

typedef __attribute__((ext_vector_type(8))) short short8;
typedef __attribute__((ext_vector_type(4))) float f32x4;

__device__ __forceinline__ float gelu_exact(float x){
  return 0.5f * x * (1.0f + erff(x * 0.70710678118654752f));
}

__device__ __forceinline__ short f2bf(float f){
  unsigned u = __float_as_uint(f);
  unsigned r = (u + 0x7FFFu + ((u >> 16) & 1u)) >> 16;
  return (short)r;
}

// ---------------- weight transpose+convert: W[K][N] fp32 -> Wt[N][K] bf16 ----
__global__ __launch_bounds__(256) void w2bft(
    const float* __restrict__ W, short* __restrict__ Wt, int K, int N)
{
  __shared__ float t[32][33];
  const int tx = threadIdx.x & 31, ty = threadIdx.x >> 5;  // 32 x 8
  const int k0 = blockIdx.y << 5, n0 = blockIdx.x << 5;
  #pragma unroll
  for (int i = 0; i < 32; i += 8)
    t[ty+i][tx] = W[(size_t)(k0+ty+i)*N + n0+tx];
  __syncthreads();
  #pragma unroll
  for (int i = 0; i < 32; i += 8)
    Wt[(size_t)(n0+ty+i)*K + k0+tx] = f2bf(t[tx][ty+i]);
}

// ---------------- x fp32 -> bf16, rows >= MTOK zeroed ----------------
__global__ __launch_bounds__(256) void x2bf(const float* __restrict__ x, short* __restrict__ xb)
{
  size_t i = ((size_t)blockIdx.x*256 + threadIdx.x) * 8;
  if (i >= (size_t)MPAD*CD) return;
  size_t row = i >> 9;
  short8 o;
  if (row < MTOK){
    #pragma unroll
    for (int j = 0; j < 8; j++) o[j] = f2bf(x[i+j]);
  } else {
    #pragma unroll
    for (int j = 0; j < 8; j++) o[j] = 0;
  }
  *(short8*)(xb + i) = o;
}

// ---------------- bf16 MFMA GEMM: C[M,N] = A[M,K] @ Bt[N,K]^T ----------------
// 128x64 tile, BK=64, 4 waves. flags: 1=bias, 2=gelu, 4=store bf16
__global__ __launch_bounds__(256) void gemm_bf16(
    const short* __restrict__ A, const short* __restrict__ Bt,
    const float* __restrict__ bias, void* __restrict__ Cm,
    int M, int N, int K, int flags)
{
  __shared__ short As[128*64];
  __shared__ short Bs[64*64];
  const int tid = threadIdx.x;
  const int lane = tid & 63, wv = tid >> 6;
  const int lc = lane & 15, lg = lane >> 4;
  const int row0 = blockIdx.y * 128, col0 = blockIdx.x * 64;
  f32x4 acc[2][4];
  #pragma unroll
  for (int rt=0;rt<2;rt++)
    #pragma unroll
    for (int ct=0;ct<4;ct++) acc[rt][ct] = (f32x4){0.f,0.f,0.f,0.f};

  for (int k0 = 0; k0 < K; k0 += 64){
    __syncthreads();
    #pragma unroll
    for (int p = 0; p < 4; p++){
      int c = tid + p*256;
      int r = c >> 3, s = c & 7;
      short8 v = *(const short8*)(A + (size_t)(row0 + r)*K + k0 + s*8);
      *(short8*)&As[r*64 + ((s ^ (r & 7))*8)] = v;
    }
    #pragma unroll
    for (int p = 0; p < 2; p++){
      int c = tid + p*256;
      int r = c >> 3, s = c & 7;
      short8 v = *(const short8*)(Bt + (size_t)(col0 + r)*K + k0 + s*8);
      *(short8*)&Bs[r*64 + ((s ^ (r & 7))*8)] = v;
    }
    __syncthreads();
    #pragma unroll
    for (int ks = 0; ks < 2; ks++){
      short8 af[2], bfr[4];
      #pragma unroll
      for (int rt = 0; rt < 2; rt++){
        int r = wv*32 + rt*16 + lc;
        af[rt] = *(const short8*)&As[r*64 + (((ks*4+lg) ^ (r & 7))*8)];
      }
      #pragma unroll
      for (int ct = 0; ct < 4; ct++){
        int r = ct*16 + lc;
        bfr[ct] = *(const short8*)&Bs[r*64 + (((ks*4+lg) ^ (r & 7))*8)];
      }
      #pragma unroll
      for (int rt = 0; rt < 2; rt++)
        #pragma unroll
        for (int ct = 0; ct < 4; ct++)
          acc[rt][ct] = __builtin_amdgcn_mfma_f32_16x16x32_bf16(af[rt], bfr[ct], acc[rt][ct], 0,0,0);
    }
  }
  #pragma unroll
  for (int rt = 0; rt < 2; rt++)
    #pragma unroll
    for (int e = 0; e < 4; e++){
      int gr = row0 + wv*32 + rt*16 + lg*4 + e;
      if (gr >= M) continue;
      #pragma unroll
      for (int ct = 0; ct < 4; ct++){
        int gc = col0 + ct*16 + lc;
        float v = acc[rt][ct][e];
        if (flags & 1) v += bias[gc];
        if (flags & 2) v = gelu_exact(v);
        if (flags & 4) ((short*)Cm)[(size_t)gr*N + gc] = f2bf(v);
        else           ((float*)Cm)[(size_t)gr*N + gc] = v;
      }
    }
}

// ---------------- Flash attention, bf16 MFMA (packed QKV, stride 1536) -------
__global__ __launch_bounds__(256) void attn_mfma(
    const short* __restrict__ qkv, float* __restrict__ glob)
{
  const int qt = blockIdx.x, h = blockIdx.y, b = blockIdx.z;
  const int tid = threadIdx.x;
  const int lane = tid & 63, wv = tid >> 6;
  const int lc = lane & 15;
  const int lg = lane >> 4;
  const int bN = b * NT;
  const int q0w = qt*64 + wv*16;

  __shared__ short Plds[4][16][72];
  __shared__ short Vt[64][72];

  short8 qf0, qf1;
  {
    const short* qbase = qkv + (size_t)(bN + q0w + lc)*QKS + h*DHD + lg*8;
    qf0 = *(const short8*)(qbase);
    qf1 = *(const short8*)(qbase + 32);
  }

  float m_old[4], l_sum[4];
  f32x4 o_acc[4];
  #pragma unroll
  for (int e=0;e<4;e++){ m_old[e] = -1e30f; l_sum[e] = 0.0f;
    o_acc[e] = (f32x4){0.f,0.f,0.f,0.f}; }

  for (int kt = 0; kt < 17; kt++){
    const int kt0 = kt*64;
    __syncthreads();
    {
      int key = tid & 63, dg = tid >> 6;
      bool valid = (kt0 + key) < NT;
      short8 a0 = {0,0,0,0,0,0,0,0}, a1 = {0,0,0,0,0,0,0,0};
      if (valid){
        const short* vrow = qkv + (size_t)(bN + kt0 + key)*QKS + 1024 + h*DHD + dg*16;
        a0 = ((const short8*)vrow)[0];
        a1 = ((const short8*)vrow)[1];
      }
      #pragma unroll
      for (int i=0;i<8;i++){ Vt[dg*16 + i][key] = a0[i]; Vt[dg*16 + 8 + i][key] = a1[i]; }
    }
    __syncthreads();

    f32x4 s[4];
    #pragma unroll
    for (int ct=0; ct<4; ct++){
      const short* kbase = qkv + (size_t)(bN + kt0 + ct*16 + lc)*QKS + 512 + h*DHD + lg*8;
      short8 kf0 = *(const short8*)(kbase);
      short8 kf1 = *(const short8*)(kbase + 32);
      f32x4 z = {0.f,0.f,0.f,0.f};
      s[ct] = __builtin_amdgcn_mfma_f32_16x16x32_bf16(qf0, kf0, z, 0,0,0);
      s[ct] = __builtin_amdgcn_mfma_f32_16x16x32_bf16(qf1, kf1, s[ct], 0,0,0);
    }
    #pragma unroll
    for (int ct=0; ct<4; ct++){
      bool kvalid = (kt0 + ct*16 + lc) < NT;
      #pragma unroll
      for (int e=0;e<4;e++) s[ct][e] = kvalid ? s[ct][e]*0.125f : -1e30f;
    }
    float rm[4];
    #pragma unroll
    for (int e=0;e<4;e++)
      rm[e] = fmaxf(fmaxf(s[0][e],s[1][e]), fmaxf(s[2][e],s[3][e]));
    #pragma unroll
    for (int msk=1; msk<16; msk<<=1)
      #pragma unroll
      for (int e=0;e<4;e++) rm[e] = fmaxf(rm[e], __shfl_xor(rm[e], msk));
    float mn[4], sc[4];
    #pragma unroll
    for (int e=0;e<4;e++){ mn[e] = fmaxf(m_old[e], rm[e]); sc[e] = expf(m_old[e]-mn[e]); m_old[e]=mn[e]; }
    float rs[4] = {0.f,0.f,0.f,0.f};
    #pragma unroll
    for (int ct=0; ct<4; ct++)
      #pragma unroll
      for (int e=0;e<4;e++){ float p = expf(s[ct][e]-mn[e]); s[ct][e]=p; rs[e]+=p; }
    #pragma unroll
    for (int msk=1; msk<16; msk<<=1)
      #pragma unroll
      for (int e=0;e<4;e++) rs[e] += __shfl_xor(rs[e], msk);
    #pragma unroll
    for (int e=0;e<4;e++) l_sum[e] = l_sum[e]*sc[e] + rs[e];
    #pragma unroll
    for (int dt=0; dt<4; dt++)
      #pragma unroll
      for (int e=0;e<4;e++) o_acc[dt][e] *= sc[e];
    #pragma unroll
    for (int ct=0; ct<4; ct++)
      #pragma unroll
      for (int e=0;e<4;e++) Plds[wv][lg*4+e][ct*16+lc] = f2bf(s[ct][e]);
    __syncthreads();

    #pragma unroll
    for (int ks=0; ks<2; ks++){
      short8 pa = *(const short8*)&Plds[wv][lc][ks*32 + lg*8];
      #pragma unroll
      for (int dt=0; dt<4; dt++){
        short8 vf = *(const short8*)&Vt[dt*16 + lc][ks*32 + lg*8];
        o_acc[dt] = __builtin_amdgcn_mfma_f32_16x16x32_bf16(pa, vf, o_acc[dt], 0,0,0);
      }
    }
  }

  #pragma unroll
  for (int e=0;e<4;e++){
    int q = q0w + lg*4 + e;
    if (q >= NT) continue;
    float inv = 1.0f / l_sum[e];
    #pragma unroll
    for (int dt=0; dt<4; dt++)
      glob[(size_t)(bN + q)*CD + h*DHD + dt*16 + lc] = o_acc[dt][e] * inv;
  }
}

// ---------------- Depthwise 3x3 SAME conv, bf16 out ----------------
__global__ __launch_bounds__(512) void dwconv(
    const float* __restrict__ x, const float* __restrict__ w, short* __restrict__ out)
{
  const int c = threadIdx.x;
  const int xx = blockIdx.x & 31;
  const int y  = (blockIdx.x >> 5) & 31;
  const int b  = blockIdx.x >> 10;
  float acc = 0.0f;
  #pragma unroll
  for (int ky = 0; ky < 3; ky++){
    int yy = y + ky - 1; if (yy < 0 || yy > 31) continue;
    #pragma unroll
    for (int kx = 0; kx < 3; kx++){
      int x2 = xx + kx - 1; if (x2 < 0 || x2 > 31) continue;
      acc += x[((size_t)(b*NT + 1 + yy*32 + x2))*CD + c] * w[(ky*3+kx)*CD + c];
    }
  }
  out[((size_t)(b*HW + y*32 + xx))*CD + c] = f2bf(acc);
}

// ---------------- GroupNorm(1) ----------------
__global__ __launch_bounds__(512) void gn_stats(const float* __restrict__ mm, float* __restrict__ tot)
{
  const int b = blockIdx.x >> 3, ch = blockIdx.x & 7;
  const int c = threadIdx.x;
  const float* base = mm + ((size_t)b*HW + ch*128)*CD + c;
  float s = 0.0f, s2 = 0.0f;
  for (int r = 0; r < 128; r++){ float v = base[(size_t)r*CD]; s += v; s2 += v*v; }
  #pragma unroll
  for (int o = 32; o > 0; o >>= 1){ s += __shfl_xor(s, o); s2 += __shfl_xor(s2, o); }
  __shared__ float rs[8], rs2[8];
  const int lane = c & 63, wv = c >> 6;
  if (lane == 0){ rs[wv] = s; rs2[wv] = s2; }
  __syncthreads();
  if (c == 0){
    float a = 0, a2 = 0;
    for (int i2 = 0; i2 < 8; i2++){ a += rs[i2]; a2 += rs2[i2]; }
    atomicAdd(&tot[b*2], a); atomicAdd(&tot[b*2+1], a2);
  }
}

__global__ void gn_finalize(const float* __restrict__ tot, float* __restrict__ musr)
{
  const int b = threadIdx.x;
  if (b >= BB) return;
  const float inv = 1.0f / ((float)HW * CD);
  float mu = tot[b*2] * inv;
  float var = tot[b*2+1] * inv - mu*mu;
  musr[b*2] = mu; musr[b*2+1] = rsqrtf(var + 1e-5f);
}

__global__ __launch_bounds__(512) void gn_apply(
    const float* __restrict__ mm, const float* __restrict__ musr,
    const float* __restrict__ g, const float* __restrict__ bb,
    float* __restrict__ out, int dogelu)
{
  const int c = threadIdx.x;
  const int p = blockIdx.x & (HW-1);
  const int b = blockIdx.x >> 10;
  const float mu = musr[b*2], rstd = musr[b*2+1];
  float v = mm[((size_t)b*HW + p)*CD + c];
  v = (v - mu) * rstd * g[c] + bb[c];
  if (dogelu) v = gelu_exact(v);
  out[((size_t)(b*NT + 1 + p))*CD + c] = v;
}

__global__ __launch_bounds__(512) void colmean_acc(const float* __restrict__ out, float* __restrict__ colsum)
{
  const int b = blockIdx.x >> 3, ch = blockIdx.x & 7;
  const int c = threadIdx.x;
  const float* base = out + ((size_t)(b*NT) + 1 + ch*128)*CD + c;
  float s = 0.0f;
  for (int r = 0; r < 128; r++) s += base[(size_t)r*CD];
  atomicAdd(&colsum[b*CD + c], s);
}

__global__ __launch_bounds__(512) void colmean_fin(const float* __restrict__ colsum, float* __restrict__ out)
{
  const int c = threadIdx.x, b = blockIdx.x;
  out[((size_t)b*NT)*CD + c] = colsum[b*CD + c] * (1.0f/HW);
}

// ---------------- FFT branch: separable direct DFTs ----------------
__global__ __launch_bounds__(512) void fft_f1(
    const float* __restrict__ x, float* __restrict__ Ur, float* __restrict__ Ui)
{
  const int c = threadIdx.x;
  const int xx = blockIdx.x & 31;
  const int b = blockIdx.x >> 5;
  __shared__ float ct[32], st[32];
  if (c < 32){ float ang = 6.283185307179586f * c / 32.0f; ct[c] = cosf(ang); st[c] = sinf(ang); }
  __syncthreads();
  float v[32];
  #pragma unroll
  for (int y = 0; y < 32; y++) v[y] = x[((size_t)(b*NT + 1 + y*32 + xx))*CD + c];
  for (int ky = 0; ky < 32; ky++){
    float sr = 0.0f, si = 0.0f;
    #pragma unroll
    for (int y = 0; y < 32; y++){
      int idx = (ky*y) & 31;
      sr += v[y]*ct[idx]; si -= v[y]*st[idx];
    }
    size_t o = ((size_t)((b*32+ky)*32+xx))*CD + c;
    Ur[o] = sr; Ui[o] = si;
  }
}

__global__ __launch_bounds__(512) void fft_f2(
    const float* __restrict__ Ur, const float* __restrict__ Ui,
    const float* __restrict__ wr, const float* __restrict__ wi,
    float* __restrict__ Gr, float* __restrict__ Gi)
{
  const int c = threadIdx.x;
  const int ky = blockIdx.x & 31;
  const int b = blockIdx.x >> 5;
  __shared__ float ct[32], st[32];
  if (c < 32){ float ang = 6.283185307179586f * c / 32.0f; ct[c] = cosf(ang); st[c] = sinf(ang); }
  __syncthreads();
  float ur[32], ui[32];
  #pragma unroll
  for (int xx = 0; xx < 32; xx++){
    size_t o = ((size_t)((b*32+ky)*32+xx))*CD + c;
    ur[xx] = Ur[o]; ui[xx] = Ui[o];
  }
  for (int kx = 0; kx < FWD; kx++){
    float ar = 0.0f, ai = 0.0f;
    #pragma unroll
    for (int xx = 0; xx < 32; xx++){
      int idx = (kx*xx) & 31;
      float cc = ct[idx], ss = st[idx];
      ar += ur[xx]*cc + ui[xx]*ss;
      ai += ui[xx]*cc - ur[xx]*ss;
    }
    size_t fo = ((size_t)(ky*FWD+kx))*CD + c;
    float fwr = wr[fo], fwi = wi[fo];
    size_t go = ((size_t)((b*32+ky)*FWD+kx))*CD + c;
    Gr[go] = ar*fwr - ai*fwi;
    Gi[go] = ar*fwi + ai*fwr;
  }
}

__global__ __launch_bounds__(512) void fft_f3(
    const float* __restrict__ Gr, const float* __restrict__ Gi,
    float* __restrict__ Tr, float* __restrict__ Ti)
{
  const int c = threadIdx.x;
  const int kx = blockIdx.x % FWD;
  const int b = blockIdx.x / FWD;
  __shared__ float ct[32], st[32];
  if (c < 32){ float ang = 6.283185307179586f * c / 32.0f; ct[c] = cosf(ang); st[c] = sinf(ang); }
  __syncthreads();
  float gr[32], gi[32];
  #pragma unroll
  for (int ky = 0; ky < 32; ky++){
    size_t o = ((size_t)((b*32+ky)*FWD+kx))*CD + c;
    gr[ky] = Gr[o]; gi[ky] = Gi[o];
  }
  for (int y = 0; y < 32; y++){
    float tr = 0.0f, ti = 0.0f;
    #pragma unroll
    for (int ky = 0; ky < 32; ky++){
      int idx = (ky*y) & 31;
      float cc = ct[idx], ss = st[idx];
      tr += gr[ky]*cc - gi[ky]*ss;
      ti += gr[ky]*ss + gi[ky]*cc;
    }
    size_t o = ((size_t)((b*32+y)*FWD+kx))*CD + c;
    Tr[o] = tr*(1.0f/32.0f); Ti[o] = ti*(1.0f/32.0f);
  }
}

__global__ __launch_bounds__(512) void fft_f4(
    const float* __restrict__ Tr, const float* __restrict__ Ti, short* __restrict__ xe)
{
  const int c = threadIdx.x;
  const int y = blockIdx.x & 31;
  const int b = blockIdx.x >> 5;
  __shared__ float ct[32], st[32];
  if (c < 32){ float ang = 6.283185307179586f * c / 32.0f; ct[c] = cosf(ang); st[c] = sinf(ang); }
  __syncthreads();
  float tr[FWD], ti[FWD];
  #pragma unroll
  for (int kx = 0; kx < FWD; kx++){
    size_t o = ((size_t)((b*32+y)*FWD+kx))*CD + c;
    tr[kx] = Tr[o]; ti[kx] = Ti[o];
  }
  for (int x2 = 0; x2 < 32; x2++){
    float acc = tr[0] + ((x2 & 1) ? -tr[16] : tr[16]);
    #pragma unroll
    for (int k2 = 1; k2 < 16; k2++){
      int idx = (k2*x2) & 31;
      acc += 2.0f*(tr[k2]*ct[idx] - ti[k2]*st[idx]);
    }
    xe[((size_t)((b*32+y)*32+x2))*CD + c] = f2bf(acc*(1.0f/32.0f));
  }
}

// ---------------- gate: concat build (bf16), gate tail + fusion ----------------
__global__ __launch_bounds__(512) void catbuild(
    const float* __restrict__ glob, const float* __restrict__ loc,
    const float* __restrict__ fr, short* __restrict__ cat)
{
  size_t idx = (size_t)blockIdx.x*512 + threadIdx.x;
  if (idx >= (size_t)MTOK*1536) return;
  size_t token = idx / 1536;
  int c = (int)(idx % 1536);
  const float* src = (c < 512) ? glob : (c < 1024 ? loc : fr);
  cat[idx] = f2bf(src[token*CD + (c & 511)]);
}

__global__ __launch_bounds__(512) void gate_fuse(
    const float* __restrict__ h1, const float* __restrict__ gW2, const float* __restrict__ gb2,
    const float* __restrict__ glob, const float* __restrict__ loc, const float* __restrict__ fr,
    short* __restrict__ fused)
{
  const int token = blockIdx.x;
  const int tid = threadIdx.x;
  __shared__ float r0[512], r1[512], r2[512];
  float p0 = 0, p1 = 0, p2 = 0;
  if (tid < 384){
    float h = h1[(size_t)token*384 + tid];
    p0 = h * gW2[tid*3+0]; p1 = h * gW2[tid*3+1]; p2 = h * gW2[tid*3+2];
  }
  r0[tid] = p0; r1[tid] = p1; r2[tid] = p2;
  __syncthreads();
  for (int s2 = 256; s2 > 0; s2 >>= 1){
    if (tid < s2){ r0[tid] += r0[tid+s2]; r1[tid] += r1[tid+s2]; r2[tid] += r2[tid+s2]; }
    __syncthreads();
  }
  __shared__ float gw[3];
  if (tid == 0){
    float l0 = r0[0] + gb2[0], l1 = r1[0] + gb2[1], l2 = r2[0] + gb2[2];
    float mx = fmaxf(l0, fmaxf(l1, l2));
    float e0 = expf(l0-mx), e1 = expf(l1-mx), e2 = expf(l2-mx);
    float inv = 1.0f/(e0+e1+e2);
    gw[0] = e0*inv; gw[1] = e1*inv; gw[2] = e2*inv;
  }
  __syncthreads();
  size_t o = (size_t)token*CD + tid;
  fused[o] = f2bf(gw[0]*glob[o] + gw[1]*loc[o] + gw[2]*fr[o]);
}

extern "C" void kernel_launch(void* const* d_in, const int* in_sizes, int n_in,
                              void* d_out, int out_size, void* d_ws, size_t ws_size,
                              hipStream_t stream)
{
  const float* x     = (const float*)d_in[0];
  const float* Wq    = (const float*)d_in[1];
  const float* Wk    = (const float*)d_in[2];
  const float* Wv    = (const float*)d_in[3];
  const float* dw_w  = (const float*)d_in[4];
  const float* pw_w  = (const float*)d_in[5];
  const float* ln_g  = (const float*)d_in[6];
  const float* ln_b  = (const float*)d_in[7];
  const float* fr_wr = (const float*)d_in[8];
  const float* fr_wi = (const float*)d_in[9];
  const float* fr_pw = (const float*)d_in[10];
  const float* fr_g  = (const float*)d_in[11];
  const float* fr_b  = (const float*)d_in[12];
  const float* g_W1  = (const float*)d_in[13];
  const float* g_b1  = (const float*)d_in[14];
  const float* g_W2  = (const float*)d_in[15];
  const float* g_b2  = (const float*)d_in[16];
  const float* Wp    = (const float*)d_in[17];
  const float* bp    = (const float*)d_in[18];

  float* ws = (float*)d_ws;
  const size_t SZ_TOK = (size_t)BB*NT*CD;        // 4,198,400 floats
  float* glob = ws;
  float* loc  = ws + SZ_TOK;
  float* fr   = ws + 2*SZ_TOK;
  float* scrA = ws + 3*SZ_TOK;                   // 8,388,608 floats
  float* scrB = scrA + 8388608;                  // 4,456,448 floats
  float* stats = scrB + 4456448;                 // 8192 floats
  float* tot    = stats;
  float* musr   = stats + 16;
  float* colsum = stats + 64;

  short* qkvb = (short*)(stats + 8192);          // 8320*1536 bf16
  short* catb = qkvb;                            // overlay (qkv dead after attn)
  short* xb   = qkvb + (size_t)MPAD*1536;        // 8320*512
  short* actb = xb + (size_t)MPAD*CD;            // 8320*512 (dw out / xe / fused)
  short* wbuf = actb + (size_t)MPAD*CD;
  short* wqkvt = wbuf;                           // [1536][512]
  short* pwt   = wqkvt + 1536*512;               // [512][512]
  short* frpwt = pwt + 512*512;
  short* gw1t  = frpwt + 512*512;                // [384][1536]
  short* wpt   = gw1t + 384*1536;                // [512][512]

  // ---- weight + activation conversion ----
  w2bft<<<dim3(16,16), 256, 0, stream>>>(Wq, wqkvt,            512, 512);
  w2bft<<<dim3(16,16), 256, 0, stream>>>(Wk, wqkvt + 512*512,  512, 512);
  w2bft<<<dim3(16,16), 256, 0, stream>>>(Wv, wqkvt + 1024*512, 512, 512);
  w2bft<<<dim3(16,16), 256, 0, stream>>>(pw_w, pwt,   512, 512);
  w2bft<<<dim3(16,16), 256, 0, stream>>>(fr_pw, frpwt, 512, 512);
  w2bft<<<dim3(12,48), 256, 0, stream>>>(g_W1, gw1t, 1536, 384);
  w2bft<<<dim3(16,16), 256, 0, stream>>>(Wp, wpt, 512, 512);
  x2bf<<<2080, 256, 0, stream>>>(x, xb);

  // ---- branch 1: packed QKV (bf16) + flash attention ----
  gemm_bf16<<<dim3(24,65), 256, 0, stream>>>(xb, wqkvt, nullptr, qkvb, MPAD, 1536, 512, 4);
  attn_mfma<<<dim3(17, NH, BB), 256, 0, stream>>>(qkvb, glob);

  // ---- branch 2: dw conv -> pw -> GroupNorm -> cls ----
  dwconv<<<BB*HW, 512, 0, stream>>>(x, dw_w, actb);
  gemm_bf16<<<dim3(8,64), 256, 0, stream>>>(actb, pwt, nullptr, scrA, 8192, 512, 512, 0);
  hipMemsetAsync(tot, 0, 16*sizeof(float), stream);
  gn_stats<<<BB*8, 512, 0, stream>>>(scrA, tot);
  gn_finalize<<<1, 64, 0, stream>>>(tot, musr);
  gn_apply<<<BB*HW, 512, 0, stream>>>(scrA, musr, ln_g, ln_b, loc, 0);
  hipMemsetAsync(colsum, 0, 4096*sizeof(float), stream);
  colmean_acc<<<BB*8, 512, 0, stream>>>(loc, colsum);
  colmean_fin<<<BB, 512, 0, stream>>>(colsum, loc);

  // ---- branch 3: FFT filter -> pw -> GroupNorm -> GELU -> cls ----
  float* Ur = scrA;            float* Ui = scrA + 4194304;
  float* Gr = scrB;            float* Gi = scrB + 2228224;
  float* Tr = scrA;            float* Ti = scrA + 2228224;
  fft_f1<<<BB*32, 512, 0, stream>>>(x, Ur, Ui);
  fft_f2<<<BB*32, 512, 0, stream>>>(Ur, Ui, fr_wr, fr_wi, Gr, Gi);
  fft_f3<<<BB*FWD, 512, 0, stream>>>(Gr, Gi, Tr, Ti);
  fft_f4<<<BB*32, 512, 0, stream>>>(Tr, Ti, actb);
  gemm_bf16<<<dim3(8,64), 256, 0, stream>>>(actb, frpwt, nullptr, scrA, 8192, 512, 512, 0);
  hipMemsetAsync(tot, 0, 16*sizeof(float), stream);
  gn_stats<<<BB*8, 512, 0, stream>>>(scrA, tot);
  gn_finalize<<<1, 64, 0, stream>>>(tot, musr);
  gn_apply<<<BB*HW, 512, 0, stream>>>(scrA, musr, fr_g, fr_b, fr, 1);
  hipMemsetAsync(colsum, 0, 4096*sizeof(float), stream);
  colmean_acc<<<BB*8, 512, 0, stream>>>(fr, colsum);
  colmean_fin<<<BB, 512, 0, stream>>>(colsum, fr);

  // ---- gate MLP + fusion + output projection ----
  size_t cat_total = (size_t)MTOK*1536;
  catbuild<<<(unsigned)((cat_total + 511)/512), 512, 0, stream>>>(glob, loc, fr, catb);
  gemm_bf16<<<dim3(6,65), 256, 0, stream>>>(catb, gw1t, g_b1, scrB, MTOK, 384, 1536, 3);
  gate_fuse<<<MTOK, 512, 0, stream>>>(scrB, g_W2, g_b2, glob, loc, fr, actb);
  gemm_bf16<<<dim3(8,65), 256, 0, stream>>>(actb, wpt, bp, d_out, MTOK, 512, 512, 1);
}